// Round 4
// baseline (303.710 us; speedup 1.0000x reference)
//
#include <hip/hip_runtime.h>
#include <math.h>

#define EPS_F 1e-6f

typedef __attribute__((ext_vector_type(8))) short short8;
typedef __attribute__((ext_vector_type(4))) float f32x4;
typedef unsigned long long ull;

static __device__ __forceinline__ unsigned short f2bf(float f) {
    unsigned u = __float_as_uint(f);
    u += 0x7fff + ((u >> 16) & 1);          // round-to-nearest-even
    return (unsigned short)(u >> 16);
}
static __device__ __forceinline__ ull pack4(float a, float b, float c, float d) {
    return (ull)f2bf(a) | ((ull)f2bf(b) << 16) | ((ull)f2bf(c) << 32) | ((ull)f2bf(d) << 48);
}
static __device__ __forceinline__ float bf2f(unsigned short s) {
    return __uint_as_float(((unsigned)s) << 16);
}

// ---------------- small kernels ----------------

__global__ void kff(const float* __restrict__ F, float* __restrict__ FF) {
    int i = blockIdx.x, j = threadIdx.x;
    float s = 0.f;
    for (int k = 0; k < 128; ++k) s += F[k*128 + i] * F[k*128 + j];
    FF[i*128 + j] = s;
}

__global__ void knorm(const float* __restrict__ FF, float* __restrict__ inv) {
    float s = 0.f;
    for (int idx = threadIdx.x; idx < 128*128; idx += 256) { float v = FF[idx]; s += v*v; }
    for (int o = 32; o > 0; o >>= 1) s += __shfl_down(s, o);
    __shared__ float wsum[4];
    int lane = threadIdx.x & 63, w = threadIdx.x >> 6;
    if (lane == 0) wsum[w] = s;
    __syncthreads();
    if (threadIdx.x == 0) inv[0] = 1.f / (sqrtf(wsum[0]+wsum[1]+wsum[2]+wsum[3]) + EPS_F);
}

// X (f32, 1M elems) -> bf16
__global__ void kxbf(const float* __restrict__ X, short* __restrict__ Xb) {
    int i = blockIdx.x*blockDim.x + threadIdx.x;    // group of 8
    const float4* p = (const float4*)(X + (size_t)i*8);
    float4 v0 = p[0], v1 = p[1];
    *(ull*)&Xb[(size_t)i*8    ] = pack4(v0.x, v0.y, v0.z, v0.w);
    *(ull*)&Xb[(size_t)i*8 + 4] = pack4(v1.x, v1.y, v1.z, v1.w);
}

// ---------------- GEMM1: Ypart[split] = Xb[128][K] * Q[K][N] (n-tile 64) --------------
// A direct from global bf16 (L2-resident), B transposed through LDS, non-atomic partials.
__global__ __launch_bounds__(256, 4) void gemm1(
    const short* __restrict__ Xb, const float* __restrict__ Q,
    float* __restrict__ Yp, int N, int K)
{
    constexpr int LDT = 40;                 // shorts per LDS row (32 data + 8 pad)
    constexpr int KC  = 1024;
    __shared__ short Bs[64 * LDT];

    const int t    = threadIdx.x;
    const int lane = t & 63;
    const int w    = t >> 6;
    const int wm   = (w >> 1) * 64;
    const int wn   = (w & 1)  * 32;
    const int l16  = lane & 15;
    const int lq   = lane >> 4;
    const int n0   = blockIdx.x * 64;
    const int kb   = blockIdx.y * KC;
    const int bn   = t & 63, bkh = t >> 6;  // staging: col, k-octet

    float* Yout = Yp + (size_t)blockIdx.y * (128 * 8192);

    f32x4 acc[4][2];
    #pragma unroll
    for (int i = 0; i < 4; ++i) { acc[i][0] = (f32x4){0,0,0,0}; acc[i][1] = (f32x4){0,0,0,0}; }

    for (int k0 = kb; k0 < kb + KC; k0 += 32) {
        // A fragments direct from global bf16 (issue before staging stores)
        short8 a[4];
        #pragma unroll
        for (int mt = 0; mt < 4; ++mt)
            a[mt] = *(const short8*)&Xb[(size_t)(wm + mt*16 + l16)*K + k0 + lq*8];

        // stage+transpose Q tile: 32k x 64n
        float vv[8];
        #pragma unroll
        for (int j = 0; j < 8; ++j)
            vv[j] = Q[(size_t)(k0 + bkh*8 + j)*N + n0 + bn];
        short8 p;
        #pragma unroll
        for (int j = 0; j < 8; ++j) p[j] = (short)f2bf(vv[j]);
        *(short8*)&Bs[bn*LDT + bkh*8] = p;
        __syncthreads();

        short8 b[2];
        b[0] = *(const short8*)&Bs[(wn      + l16)*LDT + lq*8];
        b[1] = *(const short8*)&Bs[(wn + 16 + l16)*LDT + lq*8];
        #pragma unroll
        for (int mt = 0; mt < 4; ++mt) {
            acc[mt][0] = __builtin_amdgcn_mfma_f32_16x16x32_bf16(a[mt], b[0], acc[mt][0], 0, 0, 0);
            acc[mt][1] = __builtin_amdgcn_mfma_f32_16x16x32_bf16(a[mt], b[1], acc[mt][1], 0, 0, 0);
        }
        __syncthreads();
    }

    #pragma unroll
    for (int mt = 0; mt < 4; ++mt)
        #pragma unroll
        for (int nt = 0; nt < 2; ++nt)
            #pragma unroll
            for (int r = 0; r < 4; ++r)
                Yout[(size_t)(wm + mt*16 + lq*4 + r)*N + n0 + wn + nt*16 + l16] = acc[mt][nt][r];
}

// ---------------- fused Horner (reduces GEMM1 partials, emits bf16 R k-major) ---------
__global__ __launch_bounds__(512) void horner_fused(
    const float* __restrict__ FF, const float* __restrict__ invn,
    const float* __restrict__ lam, const float* __restrict__ gam,
    const float* __restrict__ Yp, short* __restrict__ Rg, int N)
{
    constexpr int LDT = 136;                // 128 data + 8 pad shorts
    constexpr int T = 14;
    constexpr int SPL = 8;
    __shared__ short Abf[128 * LDT];        // [m][k]
    __shared__ short Rs[32 * LDT];          // [j_local][m]

    const int t    = threadIdx.x;
    const int lane = t & 63;
    const int w    = t >> 6;
    const int wm   = (w >> 1) * 32;
    const int wn   = (w & 1) * 16;
    const int l16  = lane & 15;
    const int lq   = lane >> 4;
    const int j0   = blockIdx.x * 32;

    // stage A = bf16(FF)
    #pragma unroll
    for (int i = 0; i < 8; ++i) {
        int flat = t + i*512;
        int m = flat >> 5, k4 = flat & 31;
        float4 v = *(const float4*)&FF[m*128 + k4*4];
        *(ull*)&Abf[m*LDT + k4*4] = pack4(v.x, v.y, v.z, v.w);
    }
    // stage Rs = bf16( sum_s Ypart[s][:, j0..j0+31] ), transposed
    {
        int j = t & 31, mg = t >> 5;
        float vv[8];
        #pragma unroll
        for (int r2 = 0; r2 < 8; ++r2) {
            size_t idx = (size_t)(mg*8 + r2)*N + j0 + j;
            float s = 0.f;
            #pragma unroll
            for (int sp = 0; sp < SPL; ++sp) s += Yp[(size_t)sp*(128*8192) + idx];
            vv[r2] = s;
        }
        *(ull*)&Rs[j*LDT + mg*8    ] = pack4(vv[0], vv[1], vv[2], vv[3]);
        *(ull*)&Rs[j*LDT + mg*8 + 4] = pack4(vv[4], vv[5], vv[6], vv[7]);
    }
    __syncthreads();

    const int col = j0 + wn + l16;
    float yreg[2][4];
    #pragma unroll
    for (int mt = 0; mt < 2; ++mt)
        #pragma unroll
        for (int r = 0; r < 4; ++r)
            yreg[mt][r] = bf2f((unsigned short)Rs[(wn + l16)*LDT + wm + mt*16 + lq*4 + r]);
    const float s = gam[0] * lam[col] * invn[0];

    for (int it = 0; it < T; ++it) {
        f32x4 racc[2];
        racc[0] = (f32x4){0,0,0,0};
        racc[1] = (f32x4){0,0,0,0};
        #pragma unroll
        for (int kq = 0; kq < 4; ++kq) {
            short8 b  = *(const short8*)&Rs[(wn + l16)*LDT + kq*32 + lq*8];
            short8 a0 = *(const short8*)&Abf[(wm      + l16)*LDT + kq*32 + lq*8];
            short8 a1 = *(const short8*)&Abf[(wm + 16 + l16)*LDT + kq*32 + lq*8];
            racc[0] = __builtin_amdgcn_mfma_f32_16x16x32_bf16(a0, b, racc[0], 0, 0, 0);
            racc[1] = __builtin_amdgcn_mfma_f32_16x16x32_bf16(a1, b, racc[1], 0, 0, 0);
        }
        __syncthreads();                    // reads done before overwrite
        #pragma unroll
        for (int mt = 0; mt < 2; ++mt) {
            float r0 = yreg[mt][0] + s*racc[mt][0];
            float r1 = yreg[mt][1] + s*racc[mt][1];
            float r2 = yreg[mt][2] + s*racc[mt][2];
            float r3 = yreg[mt][3] + s*racc[mt][3];
            if (it < T-1) {
                *(ull*)&Rs[(wn + l16)*LDT + wm + mt*16 + lq*4] = pack4(r0, r1, r2, r3);
            } else {
                int row = wm + mt*16 + lq*4;
                Rg[(size_t)(row+0)*N + col] = (short)f2bf(r0);
                Rg[(size_t)(row+1)*N + col] = (short)f2bf(r1);
                Rg[(size_t)(row+2)*N + col] = (short)f2bf(r2);
                Rg[(size_t)(row+3)*N + col] = (short)f2bf(r3);
            }
        }
        if (it < T-1) __syncthreads();      // writes visible for next iteration
    }
}

// ---------------- GEMM2: Z += Rg[128][K]bf16 * Q[n][K]^T, LDS-free streaming ----------
__global__ __launch_bounds__(256, 3) void gemm2(
    const short* __restrict__ Rb, const float* __restrict__ Q,
    float* __restrict__ Z, int N, int K)
{
    constexpr int KC = 1024;
    const int t    = threadIdx.x;
    const int lane = t & 63;
    const int w    = t >> 6;
    const int l16  = lane & 15;
    const int lq   = lane >> 4;
    const int i0   = blockIdx.x * 64 + w * 16;   // wave's 16 output cols
    const int kb   = blockIdx.y * KC;

    f32x4 acc[8];
    #pragma unroll
    for (int i = 0; i < 8; ++i) acc[i] = (f32x4){0,0,0,0};

    const size_t qrow = (size_t)(i0 + l16) * K;

    #pragma unroll 2
    for (int k0 = kb; k0 < kb + KC; k0 += 32) {
        float4 q0 = *(const float4*)&Q[qrow + k0 + lq*8];
        float4 q1 = *(const float4*)&Q[qrow + k0 + lq*8 + 4];
        short8 a[8];
        #pragma unroll
        for (int mt = 0; mt < 8; ++mt)
            a[mt] = *(const short8*)&Rb[(size_t)(mt*16 + l16)*K + k0 + lq*8];
        short8 b;
        b[0] = (short)f2bf(q0.x); b[1] = (short)f2bf(q0.y);
        b[2] = (short)f2bf(q0.z); b[3] = (short)f2bf(q0.w);
        b[4] = (short)f2bf(q1.x); b[5] = (short)f2bf(q1.y);
        b[6] = (short)f2bf(q1.z); b[7] = (short)f2bf(q1.w);
        #pragma unroll
        for (int mt = 0; mt < 8; ++mt)
            acc[mt] = __builtin_amdgcn_mfma_f32_16x16x32_bf16(a[mt], b, acc[mt], 0, 0, 0);
    }

    #pragma unroll
    for (int mt = 0; mt < 8; ++mt)
        #pragma unroll
        for (int r = 0; r < 4; ++r)
            atomicAdd(&Z[(size_t)(mt*16 + lq*4 + r)*N + i0 + l16], acc[mt][r]);
}

// ---------------- launch ----------------

extern "C" void kernel_launch(void* const* d_in, const int* in_sizes, int n_in,
                              void* d_out, int out_size, void* d_ws, size_t ws_size,
                              hipStream_t stream) {
    const float* X   = (const float*)d_in[0];   // 128 x 8192
    const float* F   = (const float*)d_in[1];   // 128 x 128
    const float* Q   = (const float*)d_in[2];   // 8192 x 8192
    const float* lam = (const float*)d_in[3];   // 8192
    const float* gam = (const float*)d_in[4];   // 1
    float* Z = (float*)d_out;                   // 128 x 8192 (f32)

    const int N = 8192, K = 8192;

    char* ws = (char*)d_ws;
    float* FF  = (float*)(ws);                           // 64 KB
    float* inv = (float*)(ws + 65536);                   // 4 B
    short* Xb  = (short*)(ws + 131072);                  // 2 MB
    short* Rg  = (short*)(ws + 131072 + 2097152);        // 2 MB
    float* Yp  = (float*)(ws + 131072 + 4194304);        // 8 x 4 MB partials

    hipLaunchKernelGGL(kff,   dim3(128), dim3(128), 0, stream, F, FF);
    hipLaunchKernelGGL(knorm, dim3(1),   dim3(256), 0, stream, FF, inv);
    hipLaunchKernelGGL(kxbf,  dim3(512), dim3(256), 0, stream, X, Xb);

    // GEMM1: 8 non-atomic split-K partials of Y = X @ Q
    hipLaunchKernelGGL(gemm1, dim3(128, 8), dim3(256), 0, stream, Xb, Q, Yp, N, K);

    // fused Horner: reduce partials, run Neumann series, emit bf16 R (k-major)
    hipLaunchKernelGGL(horner_fused, dim3(256), dim3(512), 0, stream,
                       FF, inv, lam, gam, Yp, Rg, N);

    // GEMM2: Z = R @ Q^T (LDS-free streaming, split-K=8 atomic)
    hipMemsetAsync(Z, 0, (size_t)128*N*sizeof(float), stream);
    hipLaunchKernelGGL(gemm2, dim3(128, 8), dim3(256), 0, stream, Rg, Q, Z, N, K);
}

// Round 5
// 186.036 us; speedup vs baseline: 1.6325x; 1.6325x over previous
//
#include <hip/hip_runtime.h>
#include <math.h>

#define EPS_F 1e-6f

typedef __attribute__((ext_vector_type(8))) short short8;
typedef __attribute__((ext_vector_type(4))) float f32x4;
typedef unsigned long long ull;

static __device__ __forceinline__ unsigned short f2bf(float f) {
    unsigned u = __float_as_uint(f);
    u += 0x7fff + ((u >> 16) & 1);          // round-to-nearest-even
    return (unsigned short)(u >> 16);
}
static __device__ __forceinline__ ull pack4(float a, float b, float c, float d) {
    return (ull)f2bf(a) | ((ull)f2bf(b) << 16) | ((ull)f2bf(c) << 32) | ((ull)f2bf(d) << 48);
}
static __device__ __forceinline__ float bf2f(unsigned short s) {
    return __uint_as_float(((unsigned)s) << 16);
}

// ---------------- small kernels ----------------

__global__ void kff(const float* __restrict__ F, float* __restrict__ FF) {
    int i = blockIdx.x, j = threadIdx.x;
    float s = 0.f;
    for (int k = 0; k < 128; ++k) s += F[k*128 + i] * F[k*128 + j];
    FF[i*128 + j] = s;
}

__global__ void knorm(const float* __restrict__ FF, float* __restrict__ inv) {
    float s = 0.f;
    for (int idx = threadIdx.x; idx < 128*128; idx += 256) { float v = FF[idx]; s += v*v; }
    for (int o = 32; o > 0; o >>= 1) s += __shfl_down(s, o);
    __shared__ float wsum[4];
    int lane = threadIdx.x & 63, w = threadIdx.x >> 6;
    if (lane == 0) wsum[w] = s;
    __syncthreads();
    if (threadIdx.x == 0) inv[0] = 1.f / (sqrtf(wsum[0]+wsum[1]+wsum[2]+wsum[3]) + EPS_F);
}

// X (f32, 1M elems) -> bf16
__global__ void kxbf(const float* __restrict__ X, short* __restrict__ Xb) {
    int i = blockIdx.x*blockDim.x + threadIdx.x;    // group of 8
    const float4* p = (const float4*)(X + (size_t)i*8);
    float4 v0 = p[0], v1 = p[1];
    *(ull*)&Xb[(size_t)i*8    ] = pack4(v0.x, v0.y, v0.z, v0.w);
    *(ull*)&Xb[(size_t)i*8 + 4] = pack4(v1.x, v1.y, v1.z, v1.w);
}

// ---------------- streaming split-K GEMM, both operands LDS-staged, double-buffered ---
// C_part[split][128][8192] = Ab[128][K](bf16) * op(B), op(B)[k][n] = TRANSB ? Qg[n][k] : Qg[k][n]
// BM=128, BN=64, BK=32, split-K=8, non-atomic partial outputs.
template<bool TRANSB>
__global__ __launch_bounds__(256) void gemm_s(
    const short* __restrict__ Ab, const float* __restrict__ Qg,
    float* __restrict__ Cp, int N, int K)
{
    constexpr int LDT = 48;                 // shorts per LDS row: 32 data + 16 pad (96 B)
    __shared__ short As[2][128 * LDT];
    __shared__ short Bs[2][64 * LDT];

    const int t    = threadIdx.x;
    const int lane = t & 63;
    const int w    = t >> 6;
    const int wm   = (w >> 1) * 64;
    const int wn   = (w & 1)  * 32;
    const int l16  = lane & 15;
    const int lq   = lane >> 4;
    const int n0   = blockIdx.x * 64;
    const int KC   = K >> 3;                // split-K = 8
    const int kb   = blockIdx.y * KC;

    float* Cout = Cp + (size_t)blockIdx.y * (128 * 8192);

    // staging decomposition
    const int ar0 = t >> 2, ako = (t & 3) * 8;      // A: rows ar0, ar0+64; k-off ako
    const int br0 = t >> 3, bko = (t & 7) * 4;      // B copy: rows br0, br0+32
    const int bn  = t & 63, bkh = t >> 6;           // B transpose: col bn, k-octet bkh

    f32x4 acc[4][2];
    #pragma unroll
    for (int i = 0; i < 4; ++i) { acc[i][0] = (f32x4){0,0,0,0}; acc[i][1] = (f32x4){0,0,0,0}; }

    short8 sa0, sa1;            // staged A regs
    float4 sb0, sb1;            // staged B regs (copy path)
    float  sbt[8];              // staged B regs (transpose path)

    const int NS = KC / 32;

    // ---- prologue: load + write tile 0
    {
        const int k0 = kb;
        sa0 = *(const short8*)&Ab[(size_t)ar0*K + k0 + ako];
        sa1 = *(const short8*)&Ab[(size_t)(ar0+64)*K + k0 + ako];
        if (TRANSB) {
            sb0 = *(const float4*)&Qg[(size_t)(n0+br0   )*K + k0 + bko];
            sb1 = *(const float4*)&Qg[(size_t)(n0+br0+32)*K + k0 + bko];
        } else {
            #pragma unroll
            for (int j = 0; j < 8; ++j)
                sbt[j] = Qg[(size_t)(k0 + bkh*8 + j)*N + n0 + bn];
        }
        *(short8*)&As[0][ar0*LDT + ako]      = sa0;
        *(short8*)&As[0][(ar0+64)*LDT + ako] = sa1;
        if (TRANSB) {
            *(ull*)&Bs[0][br0*LDT + bko]      = pack4(sb0.x, sb0.y, sb0.z, sb0.w);
            *(ull*)&Bs[0][(br0+32)*LDT + bko] = pack4(sb1.x, sb1.y, sb1.z, sb1.w);
        } else {
            short8 p;
            #pragma unroll
            for (int j = 0; j < 8; ++j) p[j] = (short)f2bf(sbt[j]);
            *(short8*)&Bs[0][bn*LDT + bkh*8] = p;
        }
    }
    __syncthreads();

    for (int ks = 0; ks < NS; ++ks) {
        const int cur = ks & 1;
        const bool more = (ks + 1 < NS);

        // ---- issue next tile's global loads early (latency hides under MFMA phase)
        if (more) {
            const int k0 = kb + (ks + 1) * 32;
            sa0 = *(const short8*)&Ab[(size_t)ar0*K + k0 + ako];
            sa1 = *(const short8*)&Ab[(size_t)(ar0+64)*K + k0 + ako];
            if (TRANSB) {
                sb0 = *(const float4*)&Qg[(size_t)(n0+br0   )*K + k0 + bko];
                sb1 = *(const float4*)&Qg[(size_t)(n0+br0+32)*K + k0 + bko];
            } else {
                #pragma unroll
                for (int j = 0; j < 8; ++j)
                    sbt[j] = Qg[(size_t)(k0 + bkh*8 + j)*N + n0 + bn];
            }
        }

        // ---- fragments + MFMA from buf[cur]
        short8 af[4], bfr[2];
        #pragma unroll
        for (int mt = 0; mt < 4; ++mt)
            af[mt] = *(const short8*)&As[cur][(wm + mt*16 + l16)*LDT + lq*8];
        bfr[0] = *(const short8*)&Bs[cur][(wn      + l16)*LDT + lq*8];
        bfr[1] = *(const short8*)&Bs[cur][(wn + 16 + l16)*LDT + lq*8];
        #pragma unroll
        for (int mt = 0; mt < 4; ++mt) {
            acc[mt][0] = __builtin_amdgcn_mfma_f32_16x16x32_bf16(af[mt], bfr[0], acc[mt][0], 0, 0, 0);
            acc[mt][1] = __builtin_amdgcn_mfma_f32_16x16x32_bf16(af[mt], bfr[1], acc[mt][1], 0, 0, 0);
        }

        // ---- write next tile to the other buffer, single barrier per K-step
        if (more) {
            const int nxt = cur ^ 1;
            *(short8*)&As[nxt][ar0*LDT + ako]      = sa0;
            *(short8*)&As[nxt][(ar0+64)*LDT + ako] = sa1;
            if (TRANSB) {
                *(ull*)&Bs[nxt][br0*LDT + bko]      = pack4(sb0.x, sb0.y, sb0.z, sb0.w);
                *(ull*)&Bs[nxt][(br0+32)*LDT + bko] = pack4(sb1.x, sb1.y, sb1.z, sb1.w);
            } else {
                short8 p;
                #pragma unroll
                for (int j = 0; j < 8; ++j) p[j] = (short)f2bf(sbt[j]);
                *(short8*)&Bs[nxt][bn*LDT + bkh*8] = p;
            }
            __syncthreads();
        }
    }

    // ---- epilogue: non-atomic partial store
    #pragma unroll
    for (int mt = 0; mt < 4; ++mt)
        #pragma unroll
        for (int nt = 0; nt < 2; ++nt)
            #pragma unroll
            for (int r = 0; r < 4; ++r)
                Cout[(size_t)(wm + mt*16 + lq*4 + r)*N + n0 + wn + nt*16 + l16] = acc[mt][nt][r];
}

// ---------------- fused Horner (reduces GEMM1 partials, emits bf16 R k-major) ---------
__global__ __launch_bounds__(512) void horner_fused(
    const float* __restrict__ FF, const float* __restrict__ invn,
    const float* __restrict__ lam, const float* __restrict__ gam,
    const float* __restrict__ Yp, short* __restrict__ Rg, int N)
{
    constexpr int LDT = 136;                // 128 data + 8 pad shorts
    constexpr int T = 14;
    constexpr int SPL = 8;
    __shared__ short Abf[128 * LDT];        // [m][k]
    __shared__ short Rs[32 * LDT];          // [j_local][m]

    const int t    = threadIdx.x;
    const int lane = t & 63;
    const int w    = t >> 6;
    const int wm   = (w >> 1) * 32;
    const int wn   = (w & 1) * 16;
    const int l16  = lane & 15;
    const int lq   = lane >> 4;
    const int j0   = blockIdx.x * 32;

    #pragma unroll
    for (int i = 0; i < 8; ++i) {
        int flat = t + i*512;
        int m = flat >> 5, k4 = flat & 31;
        float4 v = *(const float4*)&FF[m*128 + k4*4];
        *(ull*)&Abf[m*LDT + k4*4] = pack4(v.x, v.y, v.z, v.w);
    }
    {
        int j = t & 31, mg = t >> 5;
        float vv[8];
        #pragma unroll
        for (int r2 = 0; r2 < 8; ++r2) {
            size_t idx = (size_t)(mg*8 + r2)*N + j0 + j;
            float s = 0.f;
            #pragma unroll
            for (int sp = 0; sp < SPL; ++sp) s += Yp[(size_t)sp*(128*8192) + idx];
            vv[r2] = s;
        }
        *(ull*)&Rs[j*LDT + mg*8    ] = pack4(vv[0], vv[1], vv[2], vv[3]);
        *(ull*)&Rs[j*LDT + mg*8 + 4] = pack4(vv[4], vv[5], vv[6], vv[7]);
    }
    __syncthreads();

    const int col = j0 + wn + l16;
    float yreg[2][4];
    #pragma unroll
    for (int mt = 0; mt < 2; ++mt)
        #pragma unroll
        for (int r = 0; r < 4; ++r)
            yreg[mt][r] = bf2f((unsigned short)Rs[(wn + l16)*LDT + wm + mt*16 + lq*4 + r]);
    const float s = gam[0] * lam[col] * invn[0];

    for (int it = 0; it < T; ++it) {
        f32x4 racc[2];
        racc[0] = (f32x4){0,0,0,0};
        racc[1] = (f32x4){0,0,0,0};
        #pragma unroll
        for (int kq = 0; kq < 4; ++kq) {
            short8 b  = *(const short8*)&Rs[(wn + l16)*LDT + kq*32 + lq*8];
            short8 a0 = *(const short8*)&Abf[(wm      + l16)*LDT + kq*32 + lq*8];
            short8 a1 = *(const short8*)&Abf[(wm + 16 + l16)*LDT + kq*32 + lq*8];
            racc[0] = __builtin_amdgcn_mfma_f32_16x16x32_bf16(a0, b, racc[0], 0, 0, 0);
            racc[1] = __builtin_amdgcn_mfma_f32_16x16x32_bf16(a1, b, racc[1], 0, 0, 0);
        }
        __syncthreads();                    // reads done before overwrite
        #pragma unroll
        for (int mt = 0; mt < 2; ++mt) {
            float r0 = yreg[mt][0] + s*racc[mt][0];
            float r1 = yreg[mt][1] + s*racc[mt][1];
            float r2 = yreg[mt][2] + s*racc[mt][2];
            float r3 = yreg[mt][3] + s*racc[mt][3];
            if (it < T-1) {
                *(ull*)&Rs[(wn + l16)*LDT + wm + mt*16 + lq*4] = pack4(r0, r1, r2, r3);
            } else {
                int row = wm + mt*16 + lq*4;
                Rg[(size_t)(row+0)*N + col] = (short)f2bf(r0);
                Rg[(size_t)(row+1)*N + col] = (short)f2bf(r1);
                Rg[(size_t)(row+2)*N + col] = (short)f2bf(r2);
                Rg[(size_t)(row+3)*N + col] = (short)f2bf(r3);
            }
        }
        if (it < T-1) __syncthreads();
    }
}

// ---------------- Z = sum of 8 split partials ----------------
__global__ __launch_bounds__(256) void zred(const float* __restrict__ Zp,
                                            float* __restrict__ Z) {
    int i = (blockIdx.x*blockDim.x + threadIdx.x) * 4;      // float4 index
    f32x4 s = (f32x4){0,0,0,0};
    #pragma unroll
    for (int sp = 0; sp < 8; ++sp) {
        const float4 v = *(const float4*)&Zp[(size_t)sp*(128*8192) + i];
        s[0] += v.x; s[1] += v.y; s[2] += v.z; s[3] += v.w;
    }
    *(f32x4*)&Z[i] = s;
}

// ---------------- launch ----------------

extern "C" void kernel_launch(void* const* d_in, const int* in_sizes, int n_in,
                              void* d_out, int out_size, void* d_ws, size_t ws_size,
                              hipStream_t stream) {
    const float* X   = (const float*)d_in[0];   // 128 x 8192
    const float* F   = (const float*)d_in[1];   // 128 x 128
    const float* Q   = (const float*)d_in[2];   // 8192 x 8192
    const float* lam = (const float*)d_in[3];   // 8192
    const float* gam = (const float*)d_in[4];   // 1
    float* Z = (float*)d_out;                   // 128 x 8192 (f32)

    const int N = 8192, K = 8192;

    char* ws = (char*)d_ws;
    float* FF  = (float*)(ws);                               // 64 KB
    float* inv = (float*)(ws + 65536);                       // 4 B
    short* Xb  = (short*)(ws + 131072);                      // 2 MB
    short* Rg  = (short*)(ws + 131072 + 2097152);            // 2 MB
    float* Yp  = (float*)(ws + 131072 + 4194304);            // 8 x 4 MB
    float* Zp  = (float*)(ws + 131072 + 4194304 + 33554432); // 8 x 4 MB

    hipLaunchKernelGGL(kff,   dim3(128), dim3(128), 0, stream, F, FF);
    hipLaunchKernelGGL(knorm, dim3(1),   dim3(256), 0, stream, FF, inv);
    hipLaunchKernelGGL(kxbf,  dim3(512), dim3(256), 0, stream, X, Xb);

    // GEMM1: Yp[s] = Xb @ Q   (both operands LDS-staged, dbuf, no atomics)
    hipLaunchKernelGGL((gemm_s<false>), dim3(128, 8), dim3(256), 0, stream,
                       Xb, Q, Yp, N, K);

    // fused Horner: reduce partials, Neumann series, emit bf16 R (k-major)
    hipLaunchKernelGGL(horner_fused, dim3(256), dim3(512), 0, stream,
                       FF, inv, lam, gam, Yp, Rg, N);

    // GEMM2: Zp[s] = Rg @ Q^T  (B-staging is pure coalesced copy)
    hipLaunchKernelGGL((gemm_s<true>), dim3(128, 8), dim3(256), 0, stream,
                       Rg, Q, Zp, N, K);

    // Z = sum_s Zp[s]
    hipLaunchKernelGGL(zred, dim3(1024), dim3(256), 0, stream, Zp, Z);
}